// Round 6
// baseline (345.125 us; speedup 1.0000x reference)
//
#include <hip/hip_runtime.h>
#include <math.h>

#define H 128
#define RANK 16
#define SCALING 2.0f
#define LN_EPS 1e-5f
#define CHUNK 2048

typedef short bf16x8 __attribute__((ext_vector_type(8)));
typedef float f32x4 __attribute__((ext_vector_type(4)));

__device__ __forceinline__ unsigned short f2bf(float f) {
    unsigned int u = __float_as_uint(f);
    u += 0x7fffu + ((u >> 16) & 1u);
    return (unsigned short)(u >> 16);
}

__device__ __forceinline__ bf16x8 pack8(float4 a, float4 b) {
    bf16x8 r;
    r[0] = (short)f2bf(a.x); r[1] = (short)f2bf(a.y);
    r[2] = (short)f2bf(a.z); r[3] = (short)f2bf(a.w);
    r[4] = (short)f2bf(b.x); r[5] = (short)f2bf(b.y);
    r[6] = (short)f2bf(b.z); r[7] = (short)f2bf(b.w);
    return r;
}

// ---------------- degree count ----------------
__global__ void k_deg(const int* __restrict__ col, int E, int* __restrict__ deg) {
    int e = blockIdx.x * blockDim.x + threadIdx.x;
    if (e < E) atomicAdd(&deg[col[e]], 1);
}

// ---------------- dinv / rdeg ----------------
__global__ void k_dinv(const int* __restrict__ deg, int N,
                       float* __restrict__ dinv, float* __restrict__ rdeg) {
    int i = blockIdx.x * blockDim.x + threadIdx.x;
    if (i < N) {
        float d = (float)(deg[i] + 1);   // +1 self loop
        dinv[i] = rsqrtf(d);
        rdeg[i] = 1.0f / d;
    }
}

// ---------------- scan pass A: per-chunk sums ----------------
__global__ void k_chunksum(const int* __restrict__ deg, int N, int* __restrict__ chunkSum) {
    __shared__ int red[256];
    int c = blockIdx.x;
    int base = c * CHUNK;
    int s = 0;
    for (int i = threadIdx.x; i < CHUNK; i += 256) {
        int g = base + i;
        if (g < N) s += deg[g];
    }
    red[threadIdx.x] = s;
    __syncthreads();
    for (int off = 128; off > 0; off >>= 1) {
        if (threadIdx.x < off) red[threadIdx.x] += red[threadIdx.x + off];
        __syncthreads();
    }
    if (threadIdx.x == 0) chunkSum[c] = red[0];
}

// ---------------- scan pass B: sequential scan of chunk sums ----------------
__global__ void k_chunkscan(const int* __restrict__ chunkSum, int C,
                            int* __restrict__ chunkBase, int* __restrict__ offsets, int N) {
    if (threadIdx.x == 0 && blockIdx.x == 0) {
        int acc = 0;
        for (int c = 0; c < C; ++c) { chunkBase[c] = acc; acc += chunkSum[c]; }
        offsets[N] = acc;   // == E
    }
}

// ---------------- scan pass C: local exclusive scan ----------------
__global__ void k_localscan(const int* __restrict__ deg, int N, const int* __restrict__ chunkBase,
                            int* __restrict__ offsets, int* __restrict__ cursor) {
    int c = blockIdx.x, t = threadIdx.x;
    int base = c * CHUNK;
    int idx0 = base + t * 8;
    int v[8]; int tsum = 0;
    #pragma unroll
    for (int j = 0; j < 8; ++j) {
        int g = idx0 + j;
        v[j] = (g < N) ? deg[g] : 0;
        tsum += v[j];
    }
    int lane = t & 63, wv = t >> 6;
    int inc = tsum;
    #pragma unroll
    for (int off = 1; off < 64; off <<= 1) {
        int u = __shfl_up(inc, off);
        if (lane >= off) inc += u;
    }
    __shared__ int wsum[4];
    if (lane == 63) wsum[wv] = inc;
    __syncthreads();
    int wbase = 0;
    for (int w = 0; w < wv; ++w) wbase += wsum[w];
    int excl = wbase + inc - tsum + chunkBase[c];
    #pragma unroll
    for (int j = 0; j < 8; ++j) {
        int g = idx0 + j;
        if (g < N) { offsets[g] = excl; cursor[g] = excl; excl += v[j]; }
    }
}

// ---------------- CSR fill ----------------
__global__ void k_fill(const int* __restrict__ ei, int E,
                       int* __restrict__ cursor, int* __restrict__ adj) {
    int e = blockIdx.x * blockDim.x + threadIdx.x;
    if (e < E) {
        int r = ei[e];        // source
        int c = ei[E + e];    // target
        int pos = atomicAdd(&cursor[c], 1);
        adj[pos] = r;
    }
}

// ---------------- LoRA fold -> bf16, pre-swizzled into B-fragment order ----------------
__global__ void k_weff_bf(const float* __restrict__ W, const float* __restrict__ A,
                          const float* __restrict__ B, unsigned short* __restrict__ Wz) {
    int idx = blockIdx.x * blockDim.x + threadIdx.x;  // H*H
    if (idx < H * H) {
        int h = idx & (H - 1);   // output feature n
        int k = idx >> 7;
        float s = 0.f;
        #pragma unroll
        for (int r = 0; r < RANK; ++r) s = fmaf(A[r * H + k], B[h * RANK + r], s);
        float v = W[h * H + k] + SCALING * s;
        int kt = k >> 5, kk = k & 31, qd = kk >> 3, j = kk & 7;
        int nt = h >> 4, nl = h & 15;
        int lane = qd * 16 + nl;
        Wz[(((kt * 8 + nt) * 64 + lane) * 8) + j] = f2bf(v);
    }
}

// ---------------- fused gather + dual bf16-MFMA GEMM + gate + residual + LayerNorm ----
// Block = 256 threads = 4 waves; block owns 64 nodes; each wave owns a 16-node tile.
// Phase 1: wave gathers its 16 nodes' mean messages (lane = feature pair), packs bf16
//          into its own LDS rows (stride 136 shorts: 2-way bank pattern = free).
// Phase 2: same wave consumes only its own rows (no __syncthreads needed) as MFMA
//          A-fragments via single ds_read_b128 per k-tile.
#define MROW 136
__global__ __launch_bounds__(256) void k_gfused(
    const float* __restrict__ hidden,
    const int* __restrict__ offsets, const int* __restrict__ adj,
    const float* __restrict__ dinv, const float* __restrict__ rdeg,
    const unsigned short* __restrict__ Wmz, const unsigned short* __restrict__ Wgz,
    const float* __restrict__ msg_b, const float* __restrict__ gate_b,
    const float* __restrict__ gamma, const float* __restrict__ beta,
    float* __restrict__ out, int N) {
    __shared__ unsigned short msgs[64 * MROW];
    int t = threadIdx.x;
    int wid = t >> 6, lane = t & 63;
    int m0 = blockIdx.x * 64 + wid * 16;
    const float2* x2 = (const float2*)hidden;

    // ---- phase 1: gather ----
    for (int n = 0; n < 16; ++n) {
        int i = m0 + n;
        unsigned int packed = 0u;
        if (i < N) {
            float di = dinv[i];
            float2 a0 = x2[(size_t)i * 64 + lane];      // self loop
            a0.x *= di; a0.y *= di;
            float2 a1 = make_float2(0.f, 0.f);
            float2 a2 = make_float2(0.f, 0.f);
            float2 a3 = make_float2(0.f, 0.f);
            int e = offsets[i], s1 = offsets[i + 1];
            for (; e + 4 <= s1; e += 4) {
                int i0 = adj[e], i1 = adj[e + 1], i2 = adj[e + 2], i3 = adj[e + 3];
                float w0 = dinv[i0], w1 = dinv[i1], w2 = dinv[i2], w3 = dinv[i3];
                float2 v0 = x2[(size_t)i0 * 64 + lane];
                float2 v1 = x2[(size_t)i1 * 64 + lane];
                float2 v2 = x2[(size_t)i2 * 64 + lane];
                float2 v3 = x2[(size_t)i3 * 64 + lane];
                a0.x = fmaf(w0, v0.x, a0.x); a0.y = fmaf(w0, v0.y, a0.y);
                a1.x = fmaf(w1, v1.x, a1.x); a1.y = fmaf(w1, v1.y, a1.y);
                a2.x = fmaf(w2, v2.x, a2.x); a2.y = fmaf(w2, v2.y, a2.y);
                a3.x = fmaf(w3, v3.x, a3.x); a3.y = fmaf(w3, v3.y, a3.y);
            }
            if (e + 2 <= s1) {
                int i0 = adj[e], i1 = adj[e + 1];
                float w0 = dinv[i0], w1 = dinv[i1];
                float2 v0 = x2[(size_t)i0 * 64 + lane];
                float2 v1 = x2[(size_t)i1 * 64 + lane];
                a0.x = fmaf(w0, v0.x, a0.x); a0.y = fmaf(w0, v0.y, a0.y);
                a1.x = fmaf(w1, v1.x, a1.x); a1.y = fmaf(w1, v1.y, a1.y);
                e += 2;
            }
            if (e < s1) {
                int i0 = adj[e];
                float w0 = dinv[i0];
                float2 v0 = x2[(size_t)i0 * 64 + lane];
                a2.x = fmaf(w0, v0.x, a2.x); a2.y = fmaf(w0, v0.y, a2.y);
            }
            float sc = di * rdeg[i];                     // dinv_i (norm) * 1/deg (mean)
            float rx = ((a0.x + a1.x) + (a2.x + a3.x)) * sc;
            float ry = ((a0.y + a1.y) + (a2.y + a3.y)) * sc;
            packed = (unsigned int)f2bf(rx) | ((unsigned int)f2bf(ry) << 16);
        }
        ((unsigned int*)(msgs + (size_t)(wid * 16 + n) * MROW))[lane] = packed;
    }
    // no __syncthreads: each wave consumes only its own LDS rows (RAW within wave)

    if (m0 >= N) return;
    int quad = lane >> 4;   // 0..3
    int nl = lane & 15;

    int arow = m0 + nl; if (arow >= N) arow = N - 1;
    const float4* ha4 = (const float4*)(hidden + (size_t)arow * H);
    const bf16x8* mrow = (const bf16x8*)(msgs + (size_t)(wid * 16 + nl) * MROW);

    f32x4 accg[8], accm[8];
    #pragma unroll
    for (int nt = 0; nt < 8; ++nt) {
        accg[nt] = (f32x4)(0.f);
        accm[nt] = (f32x4)(0.f);
    }

    #pragma unroll
    for (int kt = 0; kt < 4; ++kt) {
        int o = kt * 8 + quad * 2;
        bf16x8 ah = pack8(ha4[o], ha4[o + 1]);
        bf16x8 am = mrow[kt * 4 + quad];
        const bf16x8* bg8 = (const bf16x8*)(Wgz + (size_t)kt * 4096);
        const bf16x8* bm8 = (const bf16x8*)(Wmz + (size_t)kt * 4096);
        #pragma unroll
        for (int nt = 0; nt < 8; ++nt) {
            bf16x8 bg = bg8[nt * 64 + lane];
            bf16x8 bm = bm8[nt * 64 + lane];
            accg[nt] = __builtin_amdgcn_mfma_f32_16x16x32_bf16(ah, bg, accg[nt], 0, 0, 0);
            accm[nt] = __builtin_amdgcn_mfma_f32_16x16x32_bf16(am, bm, accm[nt], 0, 0, 0);
        }
    }

    float gb[8], mb[8], gm[8], bt[8];
    #pragma unroll
    for (int nt = 0; nt < 8; ++nt) {
        int col = nt * 16 + nl;
        gb[nt] = gate_b[col]; mb[nt] = msg_b[col];
        gm[nt] = gamma[col];  bt[nt] = beta[col];
    }

    // C/D layout: node = m0 + quad*4 + reg, col = nt*16 + nl
    #pragma unroll
    for (int r = 0; r < 4; ++r) {
        int node = m0 + quad * 4 + r;
        int hnode = node < N ? node : N - 1;
        const float* hrow = hidden + (size_t)hnode * H;
        float xr[8]; float s = 0.f, ss = 0.f;
        #pragma unroll
        for (int nt = 0; nt < 8; ++nt) {
            int col = nt * 16 + nl;
            float g = 1.f / (1.f + __expf(-(accg[nt][r] + gb[nt])));
            float m = accm[nt][r] + mb[nt];
            float v = fmaf(g, m, hrow[col]);
            xr[nt] = v; s += v; ss = fmaf(v, v, ss);
        }
        #pragma unroll
        for (int msk = 1; msk < 16; msk <<= 1) {
            s += __shfl_xor(s, msk);
            ss += __shfl_xor(ss, msk);
        }
        float mu = s * (1.f / 128.f);
        float var = ss * (1.f / 128.f) - mu * mu;
        float rstd = rsqrtf(var + LN_EPS);
        if (node < N) {
            float* orow = out + (size_t)node * H;
            #pragma unroll
            for (int nt = 0; nt < 8; ++nt)
                orow[nt * 16 + nl] = (xr[nt] - mu) * rstd * gm[nt] + bt[nt];
        }
    }
}

extern "C" void kernel_launch(void* const* d_in, const int* in_sizes, int n_in,
                              void* d_out, int out_size, void* d_ws, size_t ws_size,
                              hipStream_t stream) {
    const float* hidden = (const float*)d_in[0];
    const int*   ei     = (const int*)d_in[1];     // (2,E) flat: row then col
    const float* msg_W  = (const float*)d_in[2];
    const float* msg_b  = (const float*)d_in[3];
    const float* msg_A  = (const float*)d_in[4];
    const float* msg_B  = (const float*)d_in[5];
    const float* gate_W = (const float*)d_in[6];
    const float* gate_b = (const float*)d_in[7];
    const float* gate_A = (const float*)d_in[8];
    const float* gate_B = (const float*)d_in[9];
    const float* gamma  = (const float*)d_in[10];
    const float* beta   = (const float*)d_in[11];
    float* out = (float*)d_out;

    int N = in_sizes[0] / H;
    int E = in_sizes[1] / 2;
    int C = (N + CHUNK - 1) / CHUNK;

    // workspace layout
    char* p = (char*)d_ws;
    unsigned short* Wmz = (unsigned short*)p;  p += (size_t)H * H * sizeof(unsigned short);
    unsigned short* Wgz = (unsigned short*)p;  p += (size_t)H * H * sizeof(unsigned short);
    float* dinv = (float*)p;               p += (size_t)N * sizeof(float);
    float* rdeg = (float*)p;               p += (size_t)N * sizeof(float);
    int*   deg  = (int*)p;                 p += (size_t)N * sizeof(int);
    int*   offsets = (int*)p;              p += (size_t)(N + 1) * sizeof(int);
    int*   cursor  = (int*)p;              p += (size_t)N * sizeof(int);
    int*   chunkSum  = (int*)p;            p += (size_t)C * sizeof(int);
    int*   chunkBase = (int*)p;            p += (size_t)C * sizeof(int);
    int*   adj  = (int*)p;                 p += (size_t)E * sizeof(int);

    hipMemsetAsync(deg, 0, (size_t)N * sizeof(int), stream);

    k_deg<<<(E + 255) / 256, 256, 0, stream>>>(ei + E, E, deg);
    k_dinv<<<(N + 255) / 256, 256, 0, stream>>>(deg, N, dinv, rdeg);
    k_chunksum<<<C, 256, 0, stream>>>(deg, N, chunkSum);
    k_chunkscan<<<1, 64, 0, stream>>>(chunkSum, C, chunkBase, offsets, N);
    k_localscan<<<C, 256, 0, stream>>>(deg, N, chunkBase, offsets, cursor);
    k_fill<<<(E + 255) / 256, 256, 0, stream>>>(ei, E, cursor, adj);
    k_weff_bf<<<(H * H + 255) / 256, 256, 0, stream>>>(msg_W, msg_A, msg_B, Wmz);
    k_weff_bf<<<(H * H + 255) / 256, 256, 0, stream>>>(gate_W, gate_A, gate_B, Wgz);
    k_gfused<<<(N + 63) / 64, 256, 0, stream>>>(
        hidden, offsets, adj, dinv, rdeg, Wmz, Wgz,
        msg_b, gate_b, gamma, beta, out, N);
}

// Round 7
// 281.638 us; speedup vs baseline: 1.2254x; 1.2254x over previous
//
#include <hip/hip_runtime.h>
#include <math.h>

#define H 128
#define RANK 16
#define SCALING 2.0f
#define LN_EPS 1e-5f
#define CHUNK 2048

typedef short bf16x8 __attribute__((ext_vector_type(8)));
typedef float f32x4 __attribute__((ext_vector_type(4)));

__device__ __forceinline__ unsigned short f2bf(float f) {
    unsigned int u = __float_as_uint(f);
    u += 0x7fffu + ((u >> 16) & 1u);
    return (unsigned short)(u >> 16);
}
__device__ __forceinline__ float bflo(unsigned int u) {
    return __uint_as_float(u << 16);
}
__device__ __forceinline__ float bfhi(unsigned int u) {
    return __uint_as_float(u & 0xffff0000u);
}

// ---------------- degree count ----------------
__global__ void k_deg(const int* __restrict__ col, int E, int* __restrict__ deg) {
    int e = blockIdx.x * blockDim.x + threadIdx.x;
    if (e < E) atomicAdd(&deg[col[e]], 1);
}

// ---------------- dinv / rdeg ----------------
__global__ void k_dinv(const int* __restrict__ deg, int N,
                       float* __restrict__ dinv, float* __restrict__ rdeg) {
    int i = blockIdx.x * blockDim.x + threadIdx.x;
    if (i < N) {
        float d = (float)(deg[i] + 1);   // +1 self loop
        dinv[i] = rsqrtf(d);
        rdeg[i] = 1.0f / d;
    }
}

// ---------------- x -> bf16 row-major (packed pairs) ----------------
__global__ void k_xbf(const float2* __restrict__ x2, int total, unsigned int* __restrict__ xb) {
    int idx = blockIdx.x * blockDim.x + threadIdx.x;   // N*64
    if (idx < total) {
        float2 v = x2[idx];
        xb[idx] = (unsigned int)f2bf(v.x) | ((unsigned int)f2bf(v.y) << 16);
    }
}

// ---------------- scan pass A: per-chunk sums ----------------
__global__ void k_chunksum(const int* __restrict__ deg, int N, int* __restrict__ chunkSum) {
    __shared__ int red[256];
    int c = blockIdx.x;
    int base = c * CHUNK;
    int s = 0;
    for (int i = threadIdx.x; i < CHUNK; i += 256) {
        int g = base + i;
        if (g < N) s += deg[g];
    }
    red[threadIdx.x] = s;
    __syncthreads();
    for (int off = 128; off > 0; off >>= 1) {
        if (threadIdx.x < off) red[threadIdx.x] += red[threadIdx.x + off];
        __syncthreads();
    }
    if (threadIdx.x == 0) chunkSum[c] = red[0];
}

// ---------------- scan pass B: sequential scan of chunk sums ----------------
__global__ void k_chunkscan(const int* __restrict__ chunkSum, int C,
                            int* __restrict__ chunkBase, int* __restrict__ offsets, int N) {
    if (threadIdx.x == 0 && blockIdx.x == 0) {
        int acc = 0;
        for (int c = 0; c < C; ++c) { chunkBase[c] = acc; acc += chunkSum[c]; }
        offsets[N] = acc;   // == E
    }
}

// ---------------- scan pass C: local exclusive scan ----------------
__global__ void k_localscan(const int* __restrict__ deg, int N, const int* __restrict__ chunkBase,
                            int* __restrict__ offsets, int* __restrict__ cursor) {
    int c = blockIdx.x, t = threadIdx.x;
    int base = c * CHUNK;
    int idx0 = base + t * 8;
    int v[8]; int tsum = 0;
    #pragma unroll
    for (int j = 0; j < 8; ++j) {
        int g = idx0 + j;
        v[j] = (g < N) ? deg[g] : 0;
        tsum += v[j];
    }
    int lane = t & 63, wv = t >> 6;
    int inc = tsum;
    #pragma unroll
    for (int off = 1; off < 64; off <<= 1) {
        int u = __shfl_up(inc, off);
        if (lane >= off) inc += u;
    }
    __shared__ int wsum[4];
    if (lane == 63) wsum[wv] = inc;
    __syncthreads();
    int wbase = 0;
    for (int w = 0; w < wv; ++w) wbase += wsum[w];
    int excl = wbase + inc - tsum + chunkBase[c];
    #pragma unroll
    for (int j = 0; j < 8; ++j) {
        int g = idx0 + j;
        if (g < N) { offsets[g] = excl; cursor[g] = excl; excl += v[j]; }
    }
}

// ---------------- CSR fill ----------------
__global__ void k_fill(const int* __restrict__ ei, int E,
                       int* __restrict__ cursor, int* __restrict__ adj) {
    int e = blockIdx.x * blockDim.x + threadIdx.x;
    if (e < E) {
        int r = ei[e];        // source
        int c = ei[E + e];    // target
        int pos = atomicAdd(&cursor[c], 1);
        adj[pos] = r;
    }
}

// ---------------- gather-reduce: one wave per node, bf16 rows, 8x edge-batched ----------------
__global__ __launch_bounds__(256) void k_gather(
    const unsigned int* __restrict__ xb, const int* __restrict__ offsets,
    const int* __restrict__ adj, const float* __restrict__ dinv,
    const float* __restrict__ rdeg, int N, unsigned int* __restrict__ msgb) {
    int wave = (blockIdx.x * 256 + threadIdx.x) >> 6;
    int lane = threadIdx.x & 63;
    if (wave >= N) return;
    int i = wave;
    float di = dinv[i];
    unsigned int su = xb[(size_t)i * 64 + lane];   // self loop
    float ax[8], ay[8];
    ax[0] = bflo(su) * di; ay[0] = bfhi(su) * di;
    #pragma unroll
    for (int j = 1; j < 8; ++j) { ax[j] = 0.f; ay[j] = 0.f; }
    int e = offsets[i], s1 = offsets[i + 1];
    for (; e + 8 <= s1; e += 8) {
        int is[8]; float ws[8]; unsigned int us[8];
        #pragma unroll
        for (int j = 0; j < 8; ++j) is[j] = adj[e + j];
        #pragma unroll
        for (int j = 0; j < 8; ++j) ws[j] = dinv[is[j]];
        #pragma unroll
        for (int j = 0; j < 8; ++j) us[j] = xb[(size_t)is[j] * 64 + lane];
        #pragma unroll
        for (int j = 0; j < 8; ++j) {
            ax[j] = fmaf(ws[j], bflo(us[j]), ax[j]);
            ay[j] = fmaf(ws[j], bfhi(us[j]), ay[j]);
        }
    }
    if (e + 4 <= s1) {
        int is[4]; float ws[4]; unsigned int us[4];
        #pragma unroll
        for (int j = 0; j < 4; ++j) is[j] = adj[e + j];
        #pragma unroll
        for (int j = 0; j < 4; ++j) ws[j] = dinv[is[j]];
        #pragma unroll
        for (int j = 0; j < 4; ++j) us[j] = xb[(size_t)is[j] * 64 + lane];
        #pragma unroll
        for (int j = 0; j < 4; ++j) {
            ax[j] = fmaf(ws[j], bflo(us[j]), ax[j]);
            ay[j] = fmaf(ws[j], bfhi(us[j]), ay[j]);
        }
        e += 4;
    }
    if (e + 2 <= s1) {
        int i0 = adj[e], i1 = adj[e + 1];
        float w0 = dinv[i0], w1 = dinv[i1];
        unsigned int u0 = xb[(size_t)i0 * 64 + lane];
        unsigned int u1 = xb[(size_t)i1 * 64 + lane];
        ax[4] = fmaf(w0, bflo(u0), ax[4]); ay[4] = fmaf(w0, bfhi(u0), ay[4]);
        ax[5] = fmaf(w1, bflo(u1), ax[5]); ay[5] = fmaf(w1, bfhi(u1), ay[5]);
        e += 2;
    }
    if (e < s1) {
        int i0 = adj[e];
        float w0 = dinv[i0];
        unsigned int u0 = xb[(size_t)i0 * 64 + lane];
        ax[6] = fmaf(w0, bflo(u0), ax[6]); ay[6] = fmaf(w0, bfhi(u0), ay[6]);
    }
    float sc = di * rdeg[i];                     // dinv_i (norm) * 1/deg (mean)
    float rx = (((ax[0] + ax[1]) + (ax[2] + ax[3])) + ((ax[4] + ax[5]) + (ax[6] + ax[7]))) * sc;
    float ry = (((ay[0] + ay[1]) + (ay[2] + ay[3])) + ((ay[4] + ay[5]) + (ay[6] + ay[7]))) * sc;
    msgb[(size_t)i * 64 + lane] = (unsigned int)f2bf(rx) | ((unsigned int)f2bf(ry) << 16);
}

// ---------------- LoRA fold -> bf16, pre-swizzled into B-fragment order ----------------
__global__ void k_weff_bf(const float* __restrict__ W, const float* __restrict__ A,
                          const float* __restrict__ B, unsigned short* __restrict__ Wz) {
    int idx = blockIdx.x * blockDim.x + threadIdx.x;  // H*H
    if (idx < H * H) {
        int h = idx & (H - 1);   // output feature n
        int k = idx >> 7;
        float s = 0.f;
        #pragma unroll
        for (int r = 0; r < RANK; ++r) s = fmaf(A[r * H + k], B[h * RANK + r], s);
        float v = W[h * H + k] + SCALING * s;
        int kt = k >> 5, kk = k & 31, qd = kk >> 3, j = kk & 7;
        int nt = h >> 4, nl = h & 15;
        int lane = qd * 16 + nl;
        Wz[(((kt * 8 + nt) * 64 + lane) * 8) + j] = f2bf(v);
    }
}

// ---------------- fused: both GEMMs (bf16 MFMA) + gate + residual + LayerNorm ----------------
__global__ __launch_bounds__(256) void k_fused(
    const unsigned int* __restrict__ xb, const unsigned int* __restrict__ msgb,
    const unsigned short* __restrict__ Wmz, const unsigned short* __restrict__ Wgz,
    const float* __restrict__ msg_b, const float* __restrict__ gate_b,
    const float* __restrict__ gamma, const float* __restrict__ beta,
    float* __restrict__ out, int N) {
    int t = threadIdx.x;
    int wid = t >> 6, lane = t & 63;
    int m0 = (blockIdx.x * 4 + wid) * 16;
    if (m0 >= N) return;

    int quad = lane >> 4;   // 0..3
    int nl = lane & 15;

    int arow = m0 + nl; if (arow >= N) arow = N - 1;
    const bf16x8* hb8 = (const bf16x8*)xb + (size_t)arow * 16;   // 16 bf16x8 per row
    const bf16x8* mb8 = (const bf16x8*)msgb + (size_t)arow * 16;

    f32x4 accg[8], accm[8];
    #pragma unroll
    for (int nt = 0; nt < 8; ++nt) {
        accg[nt] = (f32x4)(0.f);
        accm[nt] = (f32x4)(0.f);
    }

    #pragma unroll
    for (int kt = 0; kt < 4; ++kt) {
        bf16x8 ah = hb8[kt * 4 + quad];
        bf16x8 am = mb8[kt * 4 + quad];
        const bf16x8* bg8 = (const bf16x8*)(Wgz + (size_t)kt * 4096);
        const bf16x8* bm8 = (const bf16x8*)(Wmz + (size_t)kt * 4096);
        #pragma unroll
        for (int nt = 0; nt < 8; ++nt) {
            bf16x8 bg = bg8[nt * 64 + lane];
            bf16x8 bm = bm8[nt * 64 + lane];
            accg[nt] = __builtin_amdgcn_mfma_f32_16x16x32_bf16(ah, bg, accg[nt], 0, 0, 0);
            accm[nt] = __builtin_amdgcn_mfma_f32_16x16x32_bf16(am, bm, accm[nt], 0, 0, 0);
        }
    }

    float gb[8], mb[8], gm[8], bt[8];
    #pragma unroll
    for (int nt = 0; nt < 8; ++nt) {
        int col = nt * 16 + nl;
        gb[nt] = gate_b[col]; mb[nt] = msg_b[col];
        gm[nt] = gamma[col];  bt[nt] = beta[col];
    }

    const unsigned short* xs = (const unsigned short*)xb;

    // C/D layout: node = m0 + quad*4 + reg, col = nt*16 + nl
    #pragma unroll
    for (int r = 0; r < 4; ++r) {
        int node = m0 + quad * 4 + r;
        int hnode = node < N ? node : N - 1;
        const unsigned short* hrow = xs + (size_t)hnode * H;
        float xr[8]; float s = 0.f, ss = 0.f;
        #pragma unroll
        for (int nt = 0; nt < 8; ++nt) {
            int col = nt * 16 + nl;
            float hv = __uint_as_float((unsigned int)hrow[col] << 16);
            float g = 1.f / (1.f + __expf(-(accg[nt][r] + gb[nt])));
            float m = accm[nt][r] + mb[nt];
            float v = fmaf(g, m, hv);
            xr[nt] = v; s += v; ss = fmaf(v, v, ss);
        }
        #pragma unroll
        for (int msk = 1; msk < 16; msk <<= 1) {
            s += __shfl_xor(s, msk);
            ss += __shfl_xor(ss, msk);
        }
        float mu = s * (1.f / 128.f);
        float var = ss * (1.f / 128.f) - mu * mu;
        float rstd = rsqrtf(var + LN_EPS);
        if (node < N) {
            float* orow = out + (size_t)node * H;
            #pragma unroll
            for (int nt = 0; nt < 8; ++nt)
                orow[nt * 16 + nl] = (xr[nt] - mu) * rstd * gm[nt] + bt[nt];
        }
    }
}

extern "C" void kernel_launch(void* const* d_in, const int* in_sizes, int n_in,
                              void* d_out, int out_size, void* d_ws, size_t ws_size,
                              hipStream_t stream) {
    const float* hidden = (const float*)d_in[0];
    const int*   ei     = (const int*)d_in[1];     // (2,E) flat: row then col
    const float* msg_W  = (const float*)d_in[2];
    const float* msg_b  = (const float*)d_in[3];
    const float* msg_A  = (const float*)d_in[4];
    const float* msg_B  = (const float*)d_in[5];
    const float* gate_W = (const float*)d_in[6];
    const float* gate_b = (const float*)d_in[7];
    const float* gate_A = (const float*)d_in[8];
    const float* gate_B = (const float*)d_in[9];
    const float* gamma  = (const float*)d_in[10];
    const float* beta   = (const float*)d_in[11];
    float* out = (float*)d_out;

    int N = in_sizes[0] / H;
    int E = in_sizes[1] / 2;
    int C = (N + CHUNK - 1) / CHUNK;

    // workspace layout
    char* p = (char*)d_ws;
    unsigned short* Wmz = (unsigned short*)p;  p += (size_t)H * H * sizeof(unsigned short);
    unsigned short* Wgz = (unsigned short*)p;  p += (size_t)H * H * sizeof(unsigned short);
    float* dinv = (float*)p;               p += (size_t)N * sizeof(float);
    float* rdeg = (float*)p;               p += (size_t)N * sizeof(float);
    int*   deg  = (int*)p;                 p += (size_t)N * sizeof(int);
    int*   offsets = (int*)p;              p += (size_t)(N + 1) * sizeof(int);
    int*   cursor  = (int*)p;              p += (size_t)N * sizeof(int);
    int*   chunkSum  = (int*)p;            p += (size_t)C * sizeof(int);
    int*   chunkBase = (int*)p;            p += (size_t)C * sizeof(int);
    int*   adj  = (int*)p;                 p += (size_t)E * sizeof(int);
    unsigned int* xb   = (unsigned int*)p; p += (size_t)N * 64 * sizeof(unsigned int);
    unsigned int* msgb = (unsigned int*)p; p += (size_t)N * 64 * sizeof(unsigned int);

    hipMemsetAsync(deg, 0, (size_t)N * sizeof(int), stream);

    k_deg<<<(E + 255) / 256, 256, 0, stream>>>(ei + E, E, deg);
    k_dinv<<<(N + 255) / 256, 256, 0, stream>>>(deg, N, dinv, rdeg);
    k_xbf<<<((size_t)N * 64 + 255) / 256, 256, 0, stream>>>(
        (const float2*)hidden, N * 64, xb);
    k_chunksum<<<C, 256, 0, stream>>>(deg, N, chunkSum);
    k_chunkscan<<<1, 64, 0, stream>>>(chunkSum, C, chunkBase, offsets, N);
    k_localscan<<<C, 256, 0, stream>>>(deg, N, chunkBase, offsets, cursor);
    k_fill<<<(E + 255) / 256, 256, 0, stream>>>(ei, E, cursor, adj);
    k_weff_bf<<<(H * H + 255) / 256, 256, 0, stream>>>(msg_W, msg_A, msg_B, Wmz);
    k_weff_bf<<<(H * H + 255) / 256, 256, 0, stream>>>(gate_W, gate_A, gate_B, Wgz);
    k_gather<<<((size_t)N * 64 + 255) / 256, 256, 0, stream>>>(
        xb, offsets, adj, dinv, rdeg, N, msgb);
    int waves = (N + 15) / 16;
    k_fused<<<(waves + 3) / 4, 256, 0, stream>>>(
        xb, msgb, Wmz, Wgz, msg_b, gate_b, gamma, beta, out, N);
}

// Round 8
// 268.485 us; speedup vs baseline: 1.2855x; 1.0490x over previous
//
#include <hip/hip_runtime.h>
#include <math.h>

#define H 128
#define RANK 16
#define SCALING 2.0f
#define LN_EPS 1e-5f
#define CHUNK 2048

typedef short bf16x8 __attribute__((ext_vector_type(8)));
typedef float f32x4 __attribute__((ext_vector_type(4)));

__device__ __forceinline__ unsigned short f2bf(float f) {
    unsigned int u = __float_as_uint(f);
    u += 0x7fffu + ((u >> 16) & 1u);
    return (unsigned short)(u >> 16);
}
__device__ __forceinline__ float bflo(unsigned int u) {
    return __uint_as_float(u << 16);
}
__device__ __forceinline__ float bfhi(unsigned int u) {
    return __uint_as_float(u & 0xffff0000u);
}

// ---------------- mega-init: deg count | x->bf16 | LoRA folds ----------------
// Block ranges: [0,BA) deg atomics; [BA,BA+BB) xbf; [BA+BB, BA+BB+128) weff x2.
__global__ void k_init(const int* __restrict__ ei, int E, int* __restrict__ deg,
                       const float2* __restrict__ x2, int xtotal, unsigned int* __restrict__ xb,
                       const float* __restrict__ msg_W, const float* __restrict__ msg_A,
                       const float* __restrict__ msg_B,
                       const float* __restrict__ gate_W, const float* __restrict__ gate_A,
                       const float* __restrict__ gate_B,
                       unsigned short* __restrict__ Wmz, unsigned short* __restrict__ Wgz,
                       int BA, int BB) {
    int b = blockIdx.x;
    if (b < BA) {
        int e = b * 256 + threadIdx.x;
        if (e < E) atomicAdd(&deg[ei[E + e]], 1);
    } else if (b < BA + BB) {
        int idx = (b - BA) * 256 + threadIdx.x;
        if (idx < xtotal) {
            float2 v = x2[idx];
            xb[idx] = (unsigned int)f2bf(v.x) | ((unsigned int)f2bf(v.y) << 16);
        }
    } else {
        int bb = b - BA - BB;            // 0..127
        int which = bb >> 6;             // 0: msg, 1: gate
        int idx = (bb & 63) * 256 + threadIdx.x;   // H*H = 64*256
        const float* W = which ? gate_W : msg_W;
        const float* A = which ? gate_A : msg_A;
        const float* Bm = which ? gate_B : msg_B;
        unsigned short* Wz = which ? Wgz : Wmz;
        int h = idx & (H - 1);           // output feature n
        int k = idx >> 7;
        float s = 0.f;
        #pragma unroll
        for (int r = 0; r < RANK; ++r) s = fmaf(A[r * H + k], Bm[h * RANK + r], s);
        float v = W[h * H + k] + SCALING * s;
        int kt = k >> 5, kk = k & 31, qd = kk >> 3, j = kk & 7;
        int nt = h >> 4, nl = h & 15;
        int lane = qd * 16 + nl;
        Wz[(((kt * 8 + nt) * 64 + lane) * 8) + j] = f2bf(v);
    }
}

// ---------------- stage2: dinv/rdeg | per-chunk sums ----------------
// Block ranges: [0,BA) dinv; [BA, BA+C) chunksum.
__global__ void k_stage2(const int* __restrict__ deg, int N,
                         float* __restrict__ dinv, float* __restrict__ rdeg,
                         int* __restrict__ chunkSum, int BA) {
    int b = blockIdx.x;
    if (b < BA) {
        int i = b * 256 + threadIdx.x;
        if (i < N) {
            float d = (float)(deg[i] + 1);   // +1 self loop
            dinv[i] = rsqrtf(d);
            rdeg[i] = 1.0f / d;
        }
    } else {
        __shared__ int red[256];
        int c = b - BA;
        int base = c * CHUNK;
        int s = 0;
        for (int i = threadIdx.x; i < CHUNK; i += 256) {
            int g = base + i;
            if (g < N) s += deg[g];
        }
        red[threadIdx.x] = s;
        __syncthreads();
        for (int off = 128; off > 0; off >>= 1) {
            if (threadIdx.x < off) red[threadIdx.x] += red[threadIdx.x + off];
            __syncthreads();
        }
        if (threadIdx.x == 0) chunkSum[c] = red[0];
    }
}

// ---------------- local exclusive scan (computes own chunk base in-block) ----------------
__global__ void k_localscan(const int* __restrict__ deg, int N, const int* __restrict__ chunkSum,
                            int C, int* __restrict__ offsets, int* __restrict__ cursor) {
    int c = blockIdx.x, t = threadIdx.x;
    __shared__ int cbase_sh;
    __shared__ int wsum[4];
    if (t < 64) {
        int partial = 0, total = 0;
        for (int j = t; j < C; j += 64) {
            int v = chunkSum[j];
            total += v;
            if (j < c) partial += v;
        }
        #pragma unroll
        for (int off = 1; off < 64; off <<= 1) {
            partial += __shfl_xor(partial, off);
            total += __shfl_xor(total, off);
        }
        if (t == 0) {
            cbase_sh = partial;
            if (c == C - 1) offsets[N] = total;   // == E
        }
    }
    int base = c * CHUNK;
    int idx0 = base + t * 8;
    int v[8]; int tsum = 0;
    #pragma unroll
    for (int j = 0; j < 8; ++j) {
        int g = idx0 + j;
        v[j] = (g < N) ? deg[g] : 0;
        tsum += v[j];
    }
    int lane = t & 63, wv = t >> 6;
    int inc = tsum;
    #pragma unroll
    for (int off = 1; off < 64; off <<= 1) {
        int u = __shfl_up(inc, off);
        if (lane >= off) inc += u;
    }
    if (lane == 63) wsum[wv] = inc;
    __syncthreads();
    int wbase = 0;
    for (int w = 0; w < wv; ++w) wbase += wsum[w];
    int excl = wbase + inc - tsum + cbase_sh;
    #pragma unroll
    for (int j = 0; j < 8; ++j) {
        int g = idx0 + j;
        if (g < N) { offsets[g] = excl; cursor[g] = excl; excl += v[j]; }
    }
}

// ---------------- CSR fill ----------------
__global__ void k_fill(const int* __restrict__ ei, int E,
                       int* __restrict__ cursor, int* __restrict__ adj) {
    int e = blockIdx.x * blockDim.x + threadIdx.x;
    if (e < E) {
        int r = ei[e];        // source
        int c = ei[E + e];    // target
        int pos = atomicAdd(&cursor[c], 1);
        adj[pos] = r;
    }
}

// ---------------- gather-reduce: one wave per node, bf16 rows, 8x edge-batched ----------------
__global__ __launch_bounds__(256) void k_gather(
    const unsigned int* __restrict__ xb, const int* __restrict__ offsets,
    const int* __restrict__ adj, const float* __restrict__ dinv,
    const float* __restrict__ rdeg, int N, unsigned int* __restrict__ msgb) {
    int wave = (blockIdx.x * 256 + threadIdx.x) >> 6;
    int lane = threadIdx.x & 63;
    if (wave >= N) return;
    int i = wave;
    float di = dinv[i];
    unsigned int su = xb[(size_t)i * 64 + lane];   // self loop
    float ax[8], ay[8];
    ax[0] = bflo(su) * di; ay[0] = bfhi(su) * di;
    #pragma unroll
    for (int j = 1; j < 8; ++j) { ax[j] = 0.f; ay[j] = 0.f; }
    int e = offsets[i], s1 = offsets[i + 1];
    for (; e + 8 <= s1; e += 8) {
        int is[8]; float ws[8]; unsigned int us[8];
        #pragma unroll
        for (int j = 0; j < 8; ++j) is[j] = adj[e + j];
        #pragma unroll
        for (int j = 0; j < 8; ++j) ws[j] = dinv[is[j]];
        #pragma unroll
        for (int j = 0; j < 8; ++j) us[j] = xb[(size_t)is[j] * 64 + lane];
        #pragma unroll
        for (int j = 0; j < 8; ++j) {
            ax[j] = fmaf(ws[j], bflo(us[j]), ax[j]);
            ay[j] = fmaf(ws[j], bfhi(us[j]), ay[j]);
        }
    }
    if (e + 4 <= s1) {
        int is[4]; float ws[4]; unsigned int us[4];
        #pragma unroll
        for (int j = 0; j < 4; ++j) is[j] = adj[e + j];
        #pragma unroll
        for (int j = 0; j < 4; ++j) ws[j] = dinv[is[j]];
        #pragma unroll
        for (int j = 0; j < 4; ++j) us[j] = xb[(size_t)is[j] * 64 + lane];
        #pragma unroll
        for (int j = 0; j < 4; ++j) {
            ax[j] = fmaf(ws[j], bflo(us[j]), ax[j]);
            ay[j] = fmaf(ws[j], bfhi(us[j]), ay[j]);
        }
        e += 4;
    }
    if (e + 2 <= s1) {
        int i0 = adj[e], i1 = adj[e + 1];
        float w0 = dinv[i0], w1 = dinv[i1];
        unsigned int u0 = xb[(size_t)i0 * 64 + lane];
        unsigned int u1 = xb[(size_t)i1 * 64 + lane];
        ax[4] = fmaf(w0, bflo(u0), ax[4]); ay[4] = fmaf(w0, bfhi(u0), ay[4]);
        ax[5] = fmaf(w1, bflo(u1), ax[5]); ay[5] = fmaf(w1, bfhi(u1), ay[5]);
        e += 2;
    }
    if (e < s1) {
        int i0 = adj[e];
        float w0 = dinv[i0];
        unsigned int u0 = xb[(size_t)i0 * 64 + lane];
        ax[6] = fmaf(w0, bflo(u0), ax[6]); ay[6] = fmaf(w0, bfhi(u0), ay[6]);
    }
    float sc = di * rdeg[i];                     // dinv_i (norm) * 1/deg (mean)
    float rx = (((ax[0] + ax[1]) + (ax[2] + ax[3])) + ((ax[4] + ax[5]) + (ax[6] + ax[7]))) * sc;
    float ry = (((ay[0] + ay[1]) + (ay[2] + ay[3])) + ((ay[4] + ay[5]) + (ay[6] + ay[7]))) * sc;
    msgb[(size_t)i * 64 + lane] = (unsigned int)f2bf(rx) | ((unsigned int)f2bf(ry) << 16);
}

// ---------------- fused: both GEMMs (bf16 MFMA) + gate + residual + LayerNorm ----------------
__global__ __launch_bounds__(256) void k_fused(
    const unsigned int* __restrict__ xb, const unsigned int* __restrict__ msgb,
    const unsigned short* __restrict__ Wmz, const unsigned short* __restrict__ Wgz,
    const float* __restrict__ msg_b, const float* __restrict__ gate_b,
    const float* __restrict__ gamma, const float* __restrict__ beta,
    float* __restrict__ out, int N) {
    int t = threadIdx.x;
    int wid = t >> 6, lane = t & 63;
    int m0 = (blockIdx.x * 4 + wid) * 16;
    if (m0 >= N) return;

    int quad = lane >> 4;   // 0..3
    int nl = lane & 15;

    int arow = m0 + nl; if (arow >= N) arow = N - 1;
    const bf16x8* hb8 = (const bf16x8*)xb + (size_t)arow * 16;   // 16 bf16x8 per row
    const bf16x8* mb8 = (const bf16x8*)msgb + (size_t)arow * 16;

    f32x4 accg[8], accm[8];
    #pragma unroll
    for (int nt = 0; nt < 8; ++nt) {
        accg[nt] = (f32x4)(0.f);
        accm[nt] = (f32x4)(0.f);
    }

    #pragma unroll
    for (int kt = 0; kt < 4; ++kt) {
        bf16x8 ah = hb8[kt * 4 + quad];
        bf16x8 am = mb8[kt * 4 + quad];
        const bf16x8* bg8 = (const bf16x8*)(Wgz + (size_t)kt * 4096);
        const bf16x8* bm8 = (const bf16x8*)(Wmz + (size_t)kt * 4096);
        #pragma unroll
        for (int nt = 0; nt < 8; ++nt) {
            bf16x8 bg = bg8[nt * 64 + lane];
            bf16x8 bm = bm8[nt * 64 + lane];
            accg[nt] = __builtin_amdgcn_mfma_f32_16x16x32_bf16(ah, bg, accg[nt], 0, 0, 0);
            accm[nt] = __builtin_amdgcn_mfma_f32_16x16x32_bf16(am, bm, accm[nt], 0, 0, 0);
        }
    }

    float gb[8], mb[8], gm[8], bt[8];
    #pragma unroll
    for (int nt = 0; nt < 8; ++nt) {
        int col = nt * 16 + nl;
        gb[nt] = gate_b[col]; mb[nt] = msg_b[col];
        gm[nt] = gamma[col];  bt[nt] = beta[col];
    }

    const unsigned short* xs = (const unsigned short*)xb;

    // C/D layout: node = m0 + quad*4 + reg, col = nt*16 + nl
    #pragma unroll
    for (int r = 0; r < 4; ++r) {
        int node = m0 + quad * 4 + r;
        int hnode = node < N ? node : N - 1;
        const unsigned short* hrow = xs + (size_t)hnode * H;
        float xr[8]; float s = 0.f, ss = 0.f;
        #pragma unroll
        for (int nt = 0; nt < 8; ++nt) {
            int col = nt * 16 + nl;
            float hv = __uint_as_float((unsigned int)hrow[col] << 16);
            float g = 1.f / (1.f + __expf(-(accg[nt][r] + gb[nt])));
            float m = accm[nt][r] + mb[nt];
            float v = fmaf(g, m, hv);
            xr[nt] = v; s += v; ss = fmaf(v, v, ss);
        }
        #pragma unroll
        for (int msk = 1; msk < 16; msk <<= 1) {
            s += __shfl_xor(s, msk);
            ss += __shfl_xor(ss, msk);
        }
        float mu = s * (1.f / 128.f);
        float var = ss * (1.f / 128.f) - mu * mu;
        float rstd = rsqrtf(var + LN_EPS);
        if (node < N) {
            float* orow = out + (size_t)node * H;
            #pragma unroll
            for (int nt = 0; nt < 8; ++nt)
                orow[nt * 16 + nl] = (xr[nt] - mu) * rstd * gm[nt] + bt[nt];
        }
    }
}

extern "C" void kernel_launch(void* const* d_in, const int* in_sizes, int n_in,
                              void* d_out, int out_size, void* d_ws, size_t ws_size,
                              hipStream_t stream) {
    const float* hidden = (const float*)d_in[0];
    const int*   ei     = (const int*)d_in[1];     // (2,E) flat: row then col
    const float* msg_W  = (const float*)d_in[2];
    const float* msg_b  = (const float*)d_in[3];
    const float* msg_A  = (const float*)d_in[4];
    const float* msg_B  = (const float*)d_in[5];
    const float* gate_W = (const float*)d_in[6];
    const float* gate_b = (const float*)d_in[7];
    const float* gate_A = (const float*)d_in[8];
    const float* gate_B = (const float*)d_in[9];
    const float* gamma  = (const float*)d_in[10];
    const float* beta   = (const float*)d_in[11];
    float* out = (float*)d_out;

    int N = in_sizes[0] / H;
    int E = in_sizes[1] / 2;
    int C = (N + CHUNK - 1) / CHUNK;

    // workspace layout
    char* p = (char*)d_ws;
    unsigned short* Wmz = (unsigned short*)p;  p += (size_t)H * H * sizeof(unsigned short);
    unsigned short* Wgz = (unsigned short*)p;  p += (size_t)H * H * sizeof(unsigned short);
    float* dinv = (float*)p;               p += (size_t)N * sizeof(float);
    float* rdeg = (float*)p;               p += (size_t)N * sizeof(float);
    int*   deg  = (int*)p;                 p += (size_t)N * sizeof(int);
    int*   offsets = (int*)p;              p += (size_t)(N + 1) * sizeof(int);
    int*   cursor  = (int*)p;              p += (size_t)N * sizeof(int);
    int*   chunkSum  = (int*)p;            p += (size_t)C * sizeof(int);
    int*   adj  = (int*)p;                 p += (size_t)E * sizeof(int);
    unsigned int* xb   = (unsigned int*)p; p += (size_t)N * 64 * sizeof(unsigned int);
    unsigned int* msgb = (unsigned int*)p; p += (size_t)N * 64 * sizeof(unsigned int);

    hipMemsetAsync(deg, 0, (size_t)N * sizeof(int), stream);

    int xtotal = N * 64;
    int BA = (E + 255) / 256;              // deg blocks
    int BB = (xtotal + 255) / 256;         // xbf blocks
    k_init<<<BA + BB + 128, 256, 0, stream>>>(
        ei, E, deg, (const float2*)hidden, xtotal, xb,
        msg_W, msg_A, msg_B, gate_W, gate_A, gate_B, Wmz, Wgz, BA, BB);

    int BD = (N + 255) / 256;              // dinv blocks
    k_stage2<<<BD + C, 256, 0, stream>>>(deg, N, dinv, rdeg, chunkSum, BD);

    k_localscan<<<C, 256, 0, stream>>>(deg, N, chunkSum, C, offsets, cursor);
    k_fill<<<(E + 255) / 256, 256, 0, stream>>>(ei, E, cursor, adj);
    k_gather<<<((size_t)N * 64 + 255) / 256, 256, 0, stream>>>(
        xb, offsets, adj, dinv, rdeg, N, msgb);
    int waves = (N + 15) / 16;
    k_fused<<<(waves + 3) / 4, 256, 0, stream>>>(
        xb, msgb, Wmz, Wgz, msg_b, gate_b, gamma, beta, out, N);
}

// Round 10
// 266.559 us; speedup vs baseline: 1.2947x; 1.0072x over previous
//
#include <hip/hip_runtime.h>
#include <math.h>

#define H 128
#define RANK 16
#define SCALING 2.0f
#define LN_EPS 1e-5f
#define CHUNK 2048

typedef short bf16x8 __attribute__((ext_vector_type(8)));
typedef float f32x4 __attribute__((ext_vector_type(4)));

__device__ __forceinline__ unsigned short f2bf(float f) {
    unsigned int u = __float_as_uint(f);
    u += 0x7fffu + ((u >> 16) & 1u);
    return (unsigned short)(u >> 16);
}
__device__ __forceinline__ float bflo(unsigned int u) {
    return __uint_as_float(u << 16);
}
__device__ __forceinline__ float bfhi(unsigned int u) {
    return __uint_as_float(u & 0xffff0000u);
}

// ---------------- mega-init: deg count | x->bf16 | LoRA folds ----------------
// Block ranges: [0,BA) deg atomics; [BA,BA+BB) xbf; [BA+BB, BA+BB+128) weff x2.
__global__ void k_init(const int* __restrict__ ei, int E, int* __restrict__ deg,
                       const float2* __restrict__ x2, int xtotal, unsigned int* __restrict__ xb,
                       const float* __restrict__ msg_W, const float* __restrict__ msg_A,
                       const float* __restrict__ msg_B,
                       const float* __restrict__ gate_W, const float* __restrict__ gate_A,
                       const float* __restrict__ gate_B,
                       unsigned short* __restrict__ Wmz, unsigned short* __restrict__ Wgz,
                       int BA, int BB) {
    int b = blockIdx.x;
    if (b < BA) {
        int e = b * 256 + threadIdx.x;
        if (e < E) atomicAdd(&deg[ei[E + e]], 1);
    } else if (b < BA + BB) {
        int idx = (b - BA) * 256 + threadIdx.x;
        if (idx < xtotal) {
            float2 v = x2[idx];
            xb[idx] = (unsigned int)f2bf(v.x) | ((unsigned int)f2bf(v.y) << 16);
        }
    } else {
        int bb = b - BA - BB;            // 0..127
        int which = bb >> 6;             // 0: msg, 1: gate
        int idx = (bb & 63) * 256 + threadIdx.x;   // H*H = 64*256
        const float* W = which ? gate_W : msg_W;
        const float* A = which ? gate_A : msg_A;
        const float* Bm = which ? gate_B : msg_B;
        unsigned short* Wz = which ? Wgz : Wmz;
        int h = idx & (H - 1);           // output feature n
        int k = idx >> 7;
        float s = 0.f;
        #pragma unroll
        for (int r = 0; r < RANK; ++r) s = fmaf(A[r * H + k], Bm[h * RANK + r], s);
        float v = W[h * H + k] + SCALING * s;
        int kt = k >> 5, kk = k & 31, qd = kk >> 3, j = kk & 7;
        int nt = h >> 4, nl = h & 15;
        int lane = qd * 16 + nl;
        Wz[(((kt * 8 + nt) * 64 + lane) * 8) + j] = f2bf(v);
    }
}

// ---------------- stage2: dinv/rdeg | per-chunk sums ----------------
__global__ void k_stage2(const int* __restrict__ deg, int N,
                         float* __restrict__ dinv, float* __restrict__ rdeg,
                         int* __restrict__ chunkSum, int BA) {
    int b = blockIdx.x;
    if (b < BA) {
        int i = b * 256 + threadIdx.x;
        if (i < N) {
            float d = (float)(deg[i] + 1);   // +1 self loop
            dinv[i] = rsqrtf(d);
            rdeg[i] = 1.0f / d;
        }
    } else {
        __shared__ int red[256];
        int c = b - BA;
        int base = c * CHUNK;
        int s = 0;
        for (int i = threadIdx.x; i < CHUNK; i += 256) {
            int g = base + i;
            if (g < N) s += deg[g];
        }
        red[threadIdx.x] = s;
        __syncthreads();
        for (int off = 128; off > 0; off >>= 1) {
            if (threadIdx.x < off) red[threadIdx.x] += red[threadIdx.x + off];
            __syncthreads();
        }
        if (threadIdx.x == 0) chunkSum[c] = red[0];
    }
}

// ---------------- local exclusive scan (computes own chunk base in-block) ----------------
__global__ void k_localscan(const int* __restrict__ deg, int N, const int* __restrict__ chunkSum,
                            int C, int* __restrict__ offsets, int* __restrict__ cursor) {
    int c = blockIdx.x, t = threadIdx.x;
    __shared__ int cbase_sh;
    __shared__ int wsum[4];
    if (t < 64) {
        int partial = 0, total = 0;
        for (int j = t; j < C; j += 64) {
            int v = chunkSum[j];
            total += v;
            if (j < c) partial += v;
        }
        #pragma unroll
        for (int off = 1; off < 64; off <<= 1) {
            partial += __shfl_xor(partial, off);
            total += __shfl_xor(total, off);
        }
        if (t == 0) {
            cbase_sh = partial;
            if (c == C - 1) offsets[N] = total;   // == E
        }
    }
    int base = c * CHUNK;
    int idx0 = base + t * 8;
    int v[8]; int tsum = 0;
    #pragma unroll
    for (int j = 0; j < 8; ++j) {
        int g = idx0 + j;
        v[j] = (g < N) ? deg[g] : 0;
        tsum += v[j];
    }
    int lane = t & 63, wv = t >> 6;
    int inc = tsum;
    #pragma unroll
    for (int off = 1; off < 64; off <<= 1) {
        int u = __shfl_up(inc, off);
        if (lane >= off) inc += u;
    }
    if (lane == 63) wsum[wv] = inc;
    __syncthreads();
    int wbase = 0;
    for (int w = 0; w < wv; ++w) wbase += wsum[w];
    int excl = wbase + inc - tsum + cbase_sh;
    #pragma unroll
    for (int j = 0; j < 8; ++j) {
        int g = idx0 + j;
        if (g < N) { offsets[g] = excl; cursor[g] = excl; excl += v[j]; }
    }
}

// ---------------- CSR fill ----------------
__global__ void k_fill(const int* __restrict__ ei, int E,
                       int* __restrict__ cursor, int* __restrict__ adj) {
    int e = blockIdx.x * blockDim.x + threadIdx.x;
    if (e < E) {
        int r = ei[e];        // source
        int c = ei[E + e];    // target
        int pos = atomicAdd(&cursor[c], 1);
        adj[pos] = r;
    }
}

// ---------------- gather-reduce: one wave per node, branch-free predicated 8-wide ----------------
__global__ __launch_bounds__(256) void k_gather(
    const unsigned int* __restrict__ xb, const int* __restrict__ offsets,
    const int* __restrict__ adj, const float* __restrict__ dinv,
    const float* __restrict__ rdeg, int N, unsigned int* __restrict__ msgb) {
    int wave = (blockIdx.x * 256 + threadIdx.x) >> 6;
    int lane = threadIdx.x & 63;
    if (wave >= N) return;
    int i = wave;
    float di = dinv[i];
    unsigned int su = xb[(size_t)i * 64 + lane];   // self loop
    float ax[8], ay[8];
    ax[0] = bflo(su) * di; ay[0] = bfhi(su) * di;
    #pragma unroll
    for (int j = 1; j < 8; ++j) { ax[j] = 0.f; ay[j] = 0.f; }
    int s0 = offsets[i], s1 = offsets[i + 1];
    int last = s1 - 1;
    // branch-free: every iteration issues 8 loads; invalid slots clamp to the
    // last edge (L2-hit duplicate row) with weight 0.
    for (int e = s0; e < s1; e += 8) {
        int is[8]; float ws[8]; unsigned int us[8];
        #pragma unroll
        for (int j = 0; j < 8; ++j) {
            int ee = e + j;
            is[j] = adj[ee < s1 ? ee : last];
        }
        #pragma unroll
        for (int j = 0; j < 8; ++j) {
            float w = dinv[is[j]];
            ws[j] = (e + j < s1) ? w : 0.f;
        }
        #pragma unroll
        for (int j = 0; j < 8; ++j) us[j] = xb[(size_t)is[j] * 64 + lane];
        #pragma unroll
        for (int j = 0; j < 8; ++j) {
            ax[j] = fmaf(ws[j], bflo(us[j]), ax[j]);
            ay[j] = fmaf(ws[j], bfhi(us[j]), ay[j]);
        }
    }
    float sc = di * rdeg[i];                     // dinv_i (norm) * 1/deg (mean)
    float rx = (((ax[0] + ax[1]) + (ax[2] + ax[3])) + ((ax[4] + ax[5]) + (ax[6] + ax[7]))) * sc;
    float ry = (((ay[0] + ay[1]) + (ay[2] + ay[3])) + ((ay[4] + ay[5]) + (ay[6] + ay[7]))) * sc;
    msgb[(size_t)i * 64 + lane] = (unsigned int)f2bf(rx) | ((unsigned int)f2bf(ry) << 16);
}

// ---------------- fused: both GEMMs (bf16 MFMA) + gate + residual + LayerNorm ----------------
__global__ __launch_bounds__(256) void k_fused(
    const unsigned int* __restrict__ xb, const unsigned int* __restrict__ msgb,
    const unsigned short* __restrict__ Wmz, const unsigned short* __restrict__ Wgz,
    const float* __restrict__ msg_b, const float* __restrict__ gate_b,
    const float* __restrict__ gamma, const float* __restrict__ beta,
    float* __restrict__ out, int N) {
    int t = threadIdx.x;
    int wid = t >> 6, lane = t & 63;
    int m0 = (blockIdx.x * 4 + wid) * 16;
    if (m0 >= N) return;

    int quad = lane >> 4;   // 0..3
    int nl = lane & 15;

    int arow = m0 + nl; if (arow >= N) arow = N - 1;
    const bf16x8* hb8 = (const bf16x8*)xb + (size_t)arow * 16;   // 16 bf16x8 per row
    const bf16x8* mb8 = (const bf16x8*)msgb + (size_t)arow * 16;

    f32x4 accg[8], accm[8];
    #pragma unroll
    for (int nt = 0; nt < 8; ++nt) {
        accg[nt] = (f32x4)(0.f);
        accm[nt] = (f32x4)(0.f);
    }

    #pragma unroll
    for (int kt = 0; kt < 4; ++kt) {
        bf16x8 ah = hb8[kt * 4 + quad];
        bf16x8 am = mb8[kt * 4 + quad];
        const bf16x8* bg8 = (const bf16x8*)(Wgz + (size_t)kt * 4096);
        const bf16x8* bm8 = (const bf16x8*)(Wmz + (size_t)kt * 4096);
        #pragma unroll
        for (int nt = 0; nt < 8; ++nt) {
            bf16x8 bg = bg8[nt * 64 + lane];
            bf16x8 bm = bm8[nt * 64 + lane];
            accg[nt] = __builtin_amdgcn_mfma_f32_16x16x32_bf16(ah, bg, accg[nt], 0, 0, 0);
            accm[nt] = __builtin_amdgcn_mfma_f32_16x16x32_bf16(am, bm, accm[nt], 0, 0, 0);
        }
    }

    float gb[8], mb[8], gm[8], bt[8];
    #pragma unroll
    for (int nt = 0; nt < 8; ++nt) {
        int col = nt * 16 + nl;
        gb[nt] = gate_b[col]; mb[nt] = msg_b[col];
        gm[nt] = gamma[col];  bt[nt] = beta[col];
    }

    const unsigned short* xs = (const unsigned short*)xb;

    // C/D layout: node = m0 + quad*4 + reg, col = nt*16 + nl
    #pragma unroll
    for (int r = 0; r < 4; ++r) {
        int node = m0 + quad * 4 + r;
        int hnode = node < N ? node : N - 1;
        const unsigned short* hrow = xs + (size_t)hnode * H;
        float xr[8]; float s = 0.f, ss = 0.f;
        #pragma unroll
        for (int nt = 0; nt < 8; ++nt) {
            int col = nt * 16 + nl;
            float hv = __uint_as_float((unsigned int)hrow[col] << 16);
            float g = 1.f / (1.f + __expf(-(accg[nt][r] + gb[nt])));
            float m = accm[nt][r] + mb[nt];
            float v = fmaf(g, m, hv);
            xr[nt] = v; s += v; ss = fmaf(v, v, ss);
        }
        #pragma unroll
        for (int msk = 1; msk < 16; msk <<= 1) {
            s += __shfl_xor(s, msk);
            ss += __shfl_xor(ss, msk);
        }
        float mu = s * (1.f / 128.f);
        float var = ss * (1.f / 128.f) - mu * mu;
        float rstd = rsqrtf(var + LN_EPS);
        if (node < N) {
            float* orow = out + (size_t)node * H;
            #pragma unroll
            for (int nt = 0; nt < 8; ++nt)
                orow[nt * 16 + nl] = (xr[nt] - mu) * rstd * gm[nt] + bt[nt];
        }
    }
}

extern "C" void kernel_launch(void* const* d_in, const int* in_sizes, int n_in,
                              void* d_out, int out_size, void* d_ws, size_t ws_size,
                              hipStream_t stream) {
    const float* hidden = (const float*)d_in[0];
    const int*   ei     = (const int*)d_in[1];     // (2,E) flat: row then col
    const float* msg_W  = (const float*)d_in[2];
    const float* msg_b  = (const float*)d_in[3];
    const float* msg_A  = (const float*)d_in[4];
    const float* msg_B  = (const float*)d_in[5];
    const float* gate_W = (const float*)d_in[6];
    const float* gate_b = (const float*)d_in[7];
    const float* gate_A = (const float*)d_in[8];
    const float* gate_B = (const float*)d_in[9];
    const float* gamma  = (const float*)d_in[10];
    const float* beta   = (const float*)d_in[11];
    float* out = (float*)d_out;

    int N = in_sizes[0] / H;
    int E = in_sizes[1] / 2;
    int C = (N + CHUNK - 1) / CHUNK;

    // workspace layout
    char* p = (char*)d_ws;
    unsigned short* Wmz = (unsigned short*)p;  p += (size_t)H * H * sizeof(unsigned short);
    unsigned short* Wgz = (unsigned short*)p;  p += (size_t)H * H * sizeof(unsigned short);
    float* dinv = (float*)p;               p += (size_t)N * sizeof(float);
    float* rdeg = (float*)p;               p += (size_t)N * sizeof(float);
    int*   deg  = (int*)p;                 p += (size_t)N * sizeof(int);
    int*   offsets = (int*)p;              p += (size_t)(N + 1) * sizeof(int);
    int*   cursor  = (int*)p;              p += (size_t)N * sizeof(int);
    int*   chunkSum  = (int*)p;            p += (size_t)C * sizeof(int);
    int*   adj  = (int*)p;                 p += (size_t)E * sizeof(int);
    unsigned int* xb   = (unsigned int*)p; p += (size_t)N * 64 * sizeof(unsigned int);
    unsigned int* msgb = (unsigned int*)p; p += (size_t)N * 64 * sizeof(unsigned int);

    hipMemsetAsync(deg, 0, (size_t)N * sizeof(int), stream);

    int xtotal = N * 64;
    int BA = (E + 255) / 256;              // deg blocks
    int BB = (xtotal + 255) / 256;         // xbf blocks
    k_init<<<BA + BB + 128, 256, 0, stream>>>(
        ei, E, deg, (const float2*)hidden, xtotal, xb,
        msg_W, msg_A, msg_B, gate_W, gate_A, gate_B, Wmz, Wgz, BA, BB);

    int BD = (N + 255) / 256;              // dinv blocks
    k_stage2<<<BD + C, 256, 0, stream>>>(deg, N, dinv, rdeg, chunkSum, BD);

    k_localscan<<<C, 256, 0, stream>>>(deg, N, chunkSum, C, offsets, cursor);
    k_fill<<<(E + 255) / 256, 256, 0, stream>>>(ei, E, cursor, adj);
    k_gather<<<((size_t)N * 64 + 255) / 256, 256, 0, stream>>>(
        xb, offsets, adj, dinv, rdeg, N, msgb);
    int waves = (N + 15) / 16;
    k_fused<<<(waves + 3) / 4, 256, 0, stream>>>(
        xb, msgb, Wmz, Wgz, msg_b, gate_b, gamma, beta, out, N);
}

// Round 11
// 262.478 us; speedup vs baseline: 1.3149x; 1.0155x over previous
//
#include <hip/hip_runtime.h>
#include <math.h>

#define H 128
#define RANK 16
#define SCALING 2.0f
#define LN_EPS 1e-5f
#define CHUNK 2048

typedef short bf16x8 __attribute__((ext_vector_type(8)));
typedef float f32x4 __attribute__((ext_vector_type(4)));

__device__ __forceinline__ unsigned short f2bf(float f) {
    unsigned int u = __float_as_uint(f);
    u += 0x7fffu + ((u >> 16) & 1u);
    return (unsigned short)(u >> 16);
}
__device__ __forceinline__ float bflo(unsigned int u) {
    return __uint_as_float(u << 16);
}
__device__ __forceinline__ float bfhi(unsigned int u) {
    return __uint_as_float(u & 0xffff0000u);
}

// ---------------- mega-init: deg count | x->bf16 | LoRA folds ----------------
__global__ void k_init(const int* __restrict__ ei, int E, int* __restrict__ deg,
                       const float2* __restrict__ x2, int xtotal, unsigned int* __restrict__ xb,
                       const float* __restrict__ msg_W, const float* __restrict__ msg_A,
                       const float* __restrict__ msg_B,
                       const float* __restrict__ gate_W, const float* __restrict__ gate_A,
                       const float* __restrict__ gate_B,
                       unsigned short* __restrict__ Wmz, unsigned short* __restrict__ Wgz,
                       int BA, int BB) {
    int b = blockIdx.x;
    if (b < BA) {
        int e = b * 256 + threadIdx.x;
        if (e < E) atomicAdd(&deg[ei[E + e]], 1);
    } else if (b < BA + BB) {
        int idx = (b - BA) * 256 + threadIdx.x;
        if (idx < xtotal) {
            float2 v = x2[idx];
            xb[idx] = (unsigned int)f2bf(v.x) | ((unsigned int)f2bf(v.y) << 16);
        }
    } else {
        int bb = b - BA - BB;            // 0..127
        int which = bb >> 6;             // 0: msg, 1: gate
        int idx = (bb & 63) * 256 + threadIdx.x;   // H*H = 64*256
        const float* W = which ? gate_W : msg_W;
        const float* A = which ? gate_A : msg_A;
        const float* Bm = which ? gate_B : msg_B;
        unsigned short* Wz = which ? Wgz : Wmz;
        int h = idx & (H - 1);           // output feature n
        int k = idx >> 7;
        float s = 0.f;
        #pragma unroll
        for (int r = 0; r < RANK; ++r) s = fmaf(A[r * H + k], Bm[h * RANK + r], s);
        float v = W[h * H + k] + SCALING * s;
        int kt = k >> 5, kk = k & 31, qd = kk >> 3, j = kk & 7;
        int nt = h >> 4, nl = h & 15;
        int lane = qd * 16 + nl;
        Wz[(((kt * 8 + nt) * 64 + lane) * 8) + j] = f2bf(v);
    }
}

// ---------------- stage2: dinv/rdeg | per-chunk sums ----------------
__global__ void k_stage2(const int* __restrict__ deg, int N,
                         float* __restrict__ dinv, float* __restrict__ rdeg,
                         int* __restrict__ chunkSum, int BA) {
    int b = blockIdx.x;
    if (b < BA) {
        int i = b * 256 + threadIdx.x;
        if (i < N) {
            float d = (float)(deg[i] + 1);   // +1 self loop
            dinv[i] = rsqrtf(d);
            rdeg[i] = 1.0f / d;
        }
    } else {
        __shared__ int red[256];
        int c = b - BA;
        int base = c * CHUNK;
        int s = 0;
        for (int i = threadIdx.x; i < CHUNK; i += 256) {
            int g = base + i;
            if (g < N) s += deg[g];
        }
        red[threadIdx.x] = s;
        __syncthreads();
        for (int off = 128; off > 0; off >>= 1) {
            if (threadIdx.x < off) red[threadIdx.x] += red[threadIdx.x + off];
            __syncthreads();
        }
        if (threadIdx.x == 0) chunkSum[c] = red[0];
    }
}

// ---------------- local exclusive scan (computes own chunk base in-block) ----------------
__global__ void k_localscan(const int* __restrict__ deg, int N, const int* __restrict__ chunkSum,
                            int C, int* __restrict__ offsets, int* __restrict__ cursor) {
    int c = blockIdx.x, t = threadIdx.x;
    __shared__ int cbase_sh;
    __shared__ int wsum[4];
    if (t < 64) {
        int partial = 0, total = 0;
        for (int j = t; j < C; j += 64) {
            int v = chunkSum[j];
            total += v;
            if (j < c) partial += v;
        }
        #pragma unroll
        for (int off = 1; off < 64; off <<= 1) {
            partial += __shfl_xor(partial, off);
            total += __shfl_xor(total, off);
        }
        if (t == 0) {
            cbase_sh = partial;
            if (c == C - 1) offsets[N] = total;   // == E
        }
    }
    int base = c * CHUNK;
    int idx0 = base + t * 8;
    int v[8]; int tsum = 0;
    #pragma unroll
    for (int j = 0; j < 8; ++j) {
        int g = idx0 + j;
        v[j] = (g < N) ? deg[g] : 0;
        tsum += v[j];
    }
    int lane = t & 63, wv = t >> 6;
    int inc = tsum;
    #pragma unroll
    for (int off = 1; off < 64; off <<= 1) {
        int u = __shfl_up(inc, off);
        if (lane >= off) inc += u;
    }
    if (lane == 63) wsum[wv] = inc;
    __syncthreads();
    int wbase = 0;
    for (int w = 0; w < wv; ++w) wbase += wsum[w];
    int excl = wbase + inc - tsum + cbase_sh;
    #pragma unroll
    for (int j = 0; j < 8; ++j) {
        int g = idx0 + j;
        if (g < N) { offsets[g] = excl; cursor[g] = excl; excl += v[j]; }
    }
}

// ---------------- CSR fill ----------------
__global__ void k_fill(const int* __restrict__ ei, int E,
                       int* __restrict__ cursor, int* __restrict__ adj) {
    int e = blockIdx.x * blockDim.x + threadIdx.x;
    if (e < E) {
        int r = ei[e];        // source
        int c = ei[E + e];    // target
        int pos = atomicAdd(&cursor[c], 1);
        adj[pos] = r;
    }
}

// ---------------- gather-reduce: one wave per node, SCALARIZED index/weight loads ----
// Node index is wave-uniform; readfirstlane forces SGPR addressing so adj/dinv/offsets
// become s_loads (adj runs -> s_load_dwordx8). Only row loads stay vector.
__global__ __launch_bounds__(256) void k_gather(
    const unsigned int* __restrict__ xb, const int* __restrict__ offsets,
    const int* __restrict__ adj, const float* __restrict__ dinv,
    const float* __restrict__ rdeg, int N, unsigned int* __restrict__ msgb) {
    int wave = (blockIdx.x * 256 + threadIdx.x) >> 6;
    int lane = threadIdx.x & 63;
    if (wave >= N) return;
    int i = __builtin_amdgcn_readfirstlane(wave);
    float di = dinv[i];
    unsigned int su = xb[(size_t)i * 64 + lane];   // self loop
    float ax[8], ay[8];
    ax[0] = bflo(su) * di; ay[0] = bfhi(su) * di;
    #pragma unroll
    for (int j = 1; j < 8; ++j) { ax[j] = 0.f; ay[j] = 0.f; }
    int s0 = offsets[i], s1 = offsets[i + 1];
    int last = s1 - 1;
    for (int e = s0; e < s1; e += 8) {
        int is[8]; float ws[8]; unsigned int us[8];
        #pragma unroll
        for (int j = 0; j < 8; ++j) {
            int ee = e + j;
            is[j] = __builtin_amdgcn_readfirstlane(adj[ee < s1 ? ee : last]);
        }
        #pragma unroll
        for (int j = 0; j < 8; ++j) {
            float w = dinv[is[j]];
            ws[j] = (e + j < s1) ? w : 0.f;
        }
        #pragma unroll
        for (int j = 0; j < 8; ++j) us[j] = xb[(size_t)is[j] * 64 + lane];
        #pragma unroll
        for (int j = 0; j < 8; ++j) {
            ax[j] = fmaf(ws[j], bflo(us[j]), ax[j]);
            ay[j] = fmaf(ws[j], bfhi(us[j]), ay[j]);
        }
    }
    float sc = di * rdeg[i];                     // dinv_i (norm) * 1/deg (mean)
    float rx = (((ax[0] + ax[1]) + (ax[2] + ax[3])) + ((ax[4] + ax[5]) + (ax[6] + ax[7]))) * sc;
    float ry = (((ay[0] + ay[1]) + (ay[2] + ay[3])) + ((ay[4] + ay[5]) + (ay[6] + ay[7]))) * sc;
    msgb[(size_t)i * 64 + lane] = (unsigned int)f2bf(rx) | ((unsigned int)f2bf(ry) << 16);
}

// ---------------- fused: both GEMMs (bf16 MFMA) + gate + residual + LayerNorm ----------------
__global__ __launch_bounds__(256) void k_fused(
    const unsigned int* __restrict__ xb, const unsigned int* __restrict__ msgb,
    const unsigned short* __restrict__ Wmz, const unsigned short* __restrict__ Wgz,
    const float* __restrict__ msg_b, const float* __restrict__ gate_b,
    const float* __restrict__ gamma, const float* __restrict__ beta,
    float* __restrict__ out, int N) {
    int t = threadIdx.x;
    int wid = t >> 6, lane = t & 63;
    int m0 = (blockIdx.x * 4 + wid) * 16;
    if (m0 >= N) return;

    int quad = lane >> 4;   // 0..3
    int nl = lane & 15;

    int arow = m0 + nl; if (arow >= N) arow = N - 1;
    const bf16x8* hb8 = (const bf16x8*)xb + (size_t)arow * 16;   // 16 bf16x8 per row
    const bf16x8* mb8 = (const bf16x8*)msgb + (size_t)arow * 16;

    f32x4 accg[8], accm[8];
    #pragma unroll
    for (int nt = 0; nt < 8; ++nt) {
        accg[nt] = (f32x4)(0.f);
        accm[nt] = (f32x4)(0.f);
    }

    #pragma unroll
    for (int kt = 0; kt < 4; ++kt) {
        bf16x8 ah = hb8[kt * 4 + quad];
        bf16x8 am = mb8[kt * 4 + quad];
        const bf16x8* bg8 = (const bf16x8*)(Wgz + (size_t)kt * 4096);
        const bf16x8* bm8 = (const bf16x8*)(Wmz + (size_t)kt * 4096);
        #pragma unroll
        for (int nt = 0; nt < 8; ++nt) {
            bf16x8 bg = bg8[nt * 64 + lane];
            bf16x8 bm = bm8[nt * 64 + lane];
            accg[nt] = __builtin_amdgcn_mfma_f32_16x16x32_bf16(ah, bg, accg[nt], 0, 0, 0);
            accm[nt] = __builtin_amdgcn_mfma_f32_16x16x32_bf16(am, bm, accm[nt], 0, 0, 0);
        }
    }

    float gb[8], mb[8], gm[8], bt[8];
    #pragma unroll
    for (int nt = 0; nt < 8; ++nt) {
        int col = nt * 16 + nl;
        gb[nt] = gate_b[col]; mb[nt] = msg_b[col];
        gm[nt] = gamma[col];  bt[nt] = beta[col];
    }

    const unsigned short* xs = (const unsigned short*)xb;

    // C/D layout: node = m0 + quad*4 + reg, col = nt*16 + nl
    #pragma unroll
    for (int r = 0; r < 4; ++r) {
        int node = m0 + quad * 4 + r;
        int hnode = node < N ? node : N - 1;
        const unsigned short* hrow = xs + (size_t)hnode * H;
        float xr[8]; float s = 0.f, ss = 0.f;
        #pragma unroll
        for (int nt = 0; nt < 8; ++nt) {
            int col = nt * 16 + nl;
            float hv = __uint_as_float((unsigned int)hrow[col] << 16);
            float g = 1.f / (1.f + __expf(-(accg[nt][r] + gb[nt])));
            float m = accm[nt][r] + mb[nt];
            float v = fmaf(g, m, hv);
            xr[nt] = v; s += v; ss = fmaf(v, v, ss);
        }
        #pragma unroll
        for (int msk = 1; msk < 16; msk <<= 1) {
            s += __shfl_xor(s, msk);
            ss += __shfl_xor(ss, msk);
        }
        float mu = s * (1.f / 128.f);
        float var = ss * (1.f / 128.f) - mu * mu;
        float rstd = rsqrtf(var + LN_EPS);
        if (node < N) {
            float* orow = out + (size_t)node * H;
            #pragma unroll
            for (int nt = 0; nt < 8; ++nt)
                orow[nt * 16 + nl] = (xr[nt] - mu) * rstd * gm[nt] + bt[nt];
        }
    }
}

extern "C" void kernel_launch(void* const* d_in, const int* in_sizes, int n_in,
                              void* d_out, int out_size, void* d_ws, size_t ws_size,
                              hipStream_t stream) {
    const float* hidden = (const float*)d_in[0];
    const int*   ei     = (const int*)d_in[1];     // (2,E) flat: row then col
    const float* msg_W  = (const float*)d_in[2];
    const float* msg_b  = (const float*)d_in[3];
    const float* msg_A  = (const float*)d_in[4];
    const float* msg_B  = (const float*)d_in[5];
    const float* gate_W = (const float*)d_in[6];
    const float* gate_b = (const float*)d_in[7];
    const float* gate_A = (const float*)d_in[8];
    const float* gate_B = (const float*)d_in[9];
    const float* gamma  = (const float*)d_in[10];
    const float* beta   = (const float*)d_in[11];
    float* out = (float*)d_out;

    int N = in_sizes[0] / H;
    int E = in_sizes[1] / 2;
    int C = (N + CHUNK - 1) / CHUNK;

    // workspace layout
    char* p = (char*)d_ws;
    unsigned short* Wmz = (unsigned short*)p;  p += (size_t)H * H * sizeof(unsigned short);
    unsigned short* Wgz = (unsigned short*)p;  p += (size_t)H * H * sizeof(unsigned short);
    float* dinv = (float*)p;               p += (size_t)N * sizeof(float);
    float* rdeg = (float*)p;               p += (size_t)N * sizeof(float);
    int*   deg  = (int*)p;                 p += (size_t)N * sizeof(int);
    int*   offsets = (int*)p;              p += (size_t)(N + 1) * sizeof(int);
    int*   cursor  = (int*)p;              p += (size_t)N * sizeof(int);
    int*   chunkSum  = (int*)p;            p += (size_t)C * sizeof(int);
    int*   adj  = (int*)p;                 p += (size_t)E * sizeof(int);
    unsigned int* xb   = (unsigned int*)p; p += (size_t)N * 64 * sizeof(unsigned int);
    unsigned int* msgb = (unsigned int*)p; p += (size_t)N * 64 * sizeof(unsigned int);

    hipMemsetAsync(deg, 0, (size_t)N * sizeof(int), stream);

    int xtotal = N * 64;
    int BA = (E + 255) / 256;              // deg blocks
    int BB = (xtotal + 255) / 256;         // xbf blocks
    k_init<<<BA + BB + 128, 256, 0, stream>>>(
        ei, E, deg, (const float2*)hidden, xtotal, xb,
        msg_W, msg_A, msg_B, gate_W, gate_A, gate_B, Wmz, Wgz, BA, BB);

    int BD = (N + 255) / 256;              // dinv blocks
    k_stage2<<<BD + C, 256, 0, stream>>>(deg, N, dinv, rdeg, chunkSum, BD);

    k_localscan<<<C, 256, 0, stream>>>(deg, N, chunkSum, C, offsets, cursor);
    k_fill<<<(E + 255) / 256, 256, 0, stream>>>(ei, E, cursor, adj);
    k_gather<<<((size_t)N * 64 + 255) / 256, 256, 0, stream>>>(
        xb, offsets, adj, dinv, rdeg, N, msgb);
    int waves = (N + 15) / 16;
    k_fused<<<(waves + 3) / 4, 256, 0, stream>>>(
        xb, msgb, Wmz, Wgz, msg_b, gate_b, gamma, beta, out, N);
}